// Round 3
// baseline (365.978 us; speedup 1.0000x reference)
//
#include <hip/hip_runtime.h>
#include <hip/hip_bf16.h>
#include <stdint.h>

typedef __attribute__((ext_vector_type(8))) short short8;
typedef __attribute__((ext_vector_type(4))) float float4v;
typedef __attribute__((ext_vector_type(4))) unsigned int uint4v;
typedef unsigned short u16;

#if __has_builtin(__builtin_amdgcn_exp2f)
#define EXP2F(x) __builtin_amdgcn_exp2f(x)
#else
#define EXP2F(x) __expf(0.69314718056f * (x))
#endif

__device__ __forceinline__ u16 f2b(float f) {
    union { __hip_bfloat16 b; u16 u; } cv;
    cv.b = __float2bfloat16(f);
    return cv.u;
}

#define GLD16(g, l) __builtin_amdgcn_global_load_lds( \
    (const __attribute__((address_space(1))) void*)(g), \
    (__attribute__((address_space(3))) void*)(l), 16, 0, 0)

// ---------------------------------------------------------------------------
// 1) Gather even rows of x (token t <- x row 2t) and convert fp32 -> bf16.
__global__ void convert_x(const float* __restrict__ x, u16* __restrict__ xb) {
    int id = blockIdx.x * 256 + threadIdx.x;
    int row = id >> 8;
    int c4 = id & 255;
    const float4* src = reinterpret_cast<const float4*>(x + (size_t)(2 * row) * 1024) + c4;
    float4 v = *src;
    ushort4 o;
    o.x = f2b(v.x); o.y = f2b(v.y); o.z = f2b(v.z); o.w = f2b(v.w);
    *(reinterpret_cast<ushort4*>(xb + (size_t)row * 1024) + c4) = o;
}

// ---------------------------------------------------------------------------
// 2) Transpose-convert: in fp32 [K][N] -> out bf16 [N][K].
__global__ void transpose_convert(const float* __restrict__ in, u16* __restrict__ out,
                                  int K, int N) {
    __shared__ float tile[32][33];
    int n0 = blockIdx.x * 32, k0 = blockIdx.y * 32;
    int tx = threadIdx.x, ty = threadIdx.y;       // 32 x 8
#pragma unroll
    for (int i = 0; i < 4; i++)
        tile[ty + i * 8][tx] = in[(size_t)(k0 + ty + i * 8) * N + n0 + tx];
    __syncthreads();
#pragma unroll
    for (int i = 0; i < 4; i++)
        out[(size_t)(n0 + ty + i * 8) * K + k0 + tx] = f2b(tile[tx][ty + i * 8]);
}

// ---------------------------------------------------------------------------
// 3) GEMM C = A @ BT + bias.  A bf16 [M][K], BT bf16 [N][K].
// MODE 0: C fp32 [M][N].
// MODE 1: QKV split: Q cols (<1024) pre-scaled by 0.125*log2(e); Q/K -> Cqk bf16
//         [M][2048]; V -> transposed Cvt bf16 [(bn*1024+(n-2048))][1024] col=key.
template <int MODE>
__global__ __launch_bounds__(256) void gemm_bt(
    const u16* __restrict__ A, const u16* __restrict__ BT,
    const float* __restrict__ bias,
    float* __restrict__ Cf, u16* __restrict__ Cqk, u16* __restrict__ Cvt,
    int M, int N, int K) {
    __shared__ u16 As[128 * 32];
    __shared__ u16 Bs[128 * 32];
    const int tid = threadIdx.x;
    const int w = tid >> 6, l = tid & 63;
    const int q = l >> 4, c = l & 15;
    const int m0 = blockIdx.y * 128, n0 = blockIdx.x * 128;
    const int wm = (w >> 1) * 64, wn = (w & 1) * 64;

    const int srow = w * 16 + (l >> 2);
    const int scol = (l & 3) * 8;
    const u16* gA = A + (size_t)(m0 + srow) * K + scol;
    const u16* gB = BT + (size_t)(n0 + srow) * K + scol;

    float4v acc[4][4];
#pragma unroll
    for (int i = 0; i < 4; i++)
#pragma unroll
        for (int j = 0; j < 4; j++) acc[i][j] = {0.f, 0.f, 0.f, 0.f};

    char* AsB = (char*)&As[0];
    char* BsB = (char*)&Bs[0];

    for (int k0 = 0; k0 < K; k0 += 32) {
        __syncthreads();
        GLD16(gA + k0,                  AsB + w * 1024);
        GLD16(gA + (size_t)64 * K + k0, AsB + 4096 + w * 1024);
        GLD16(gB + k0,                  BsB + w * 1024);
        GLD16(gB + (size_t)64 * K + k0, BsB + 4096 + w * 1024);
        __syncthreads();
        short8 af[4], bf[4];
#pragma unroll
        for (int mt = 0; mt < 4; mt++)
            af[mt] = *reinterpret_cast<const short8*>(&As[(wm + mt * 16 + c) * 32 + q * 8]);
#pragma unroll
        for (int nt = 0; nt < 4; nt++)
            bf[nt] = *reinterpret_cast<const short8*>(&Bs[(wn + nt * 16 + c) * 32 + q * 8]);
#pragma unroll
        for (int mt = 0; mt < 4; mt++)
#pragma unroll
            for (int nt = 0; nt < 4; nt++)
                acc[mt][nt] = __builtin_amdgcn_mfma_f32_16x16x32_bf16(af[mt], bf[nt], acc[mt][nt], 0, 0, 0);
    }

    const int q4 = q * 4;
    if (MODE == 0) {
#pragma unroll
        for (int nt = 0; nt < 4; nt++) {
            int col = n0 + wn + nt * 16 + c;
            float bv = bias[col];
#pragma unroll
            for (int mt = 0; mt < 4; mt++) {
                int row = m0 + wm + mt * 16 + q4;
#pragma unroll
                for (int r = 0; r < 4; r++)
                    Cf[(size_t)(row + r) * N + col] = acc[mt][nt][r] + bv;
            }
        }
    } else {
        bool isV = (n0 + wn) >= 2048;                       // wave-uniform
        float qscale = ((n0 + wn) < 1024) ? (0.125f * 1.44269504f) : 1.0f;
#pragma unroll
        for (int nt = 0; nt < 4; nt++) {
            int col = n0 + wn + nt * 16 + c;
            float bv = bias[col];
            if (!isV) {
#pragma unroll
                for (int mt = 0; mt < 4; mt++) {
                    int row = m0 + wm + mt * 16 + q4;
#pragma unroll
                    for (int r = 0; r < 4; r++)
                        Cqk[(size_t)(row + r) * 2048 + col] = f2b((acc[mt][nt][r] + bv) * qscale);
                }
            } else {
                int hd_ = col - 2048;                       // h*64 + d
#pragma unroll
                for (int mt = 0; mt < 4; mt++) {
                    int row = m0 + wm + mt * 16 + q4;       // multiple of 4
                    int bn = row >> 10, key = row & 1023;   // key..key+3 contiguous
                    ushort4 pk;
                    pk.x = f2b(acc[mt][nt][0] + bv);
                    pk.y = f2b(acc[mt][nt][1] + bv);
                    pk.z = f2b(acc[mt][nt][2] + bv);
                    pk.w = f2b(acc[mt][nt][3] + bv);
                    *reinterpret_cast<ushort4*>(
                        &Cvt[((size_t)(bn << 10) + hd_) * 1024 + key]) = pk;
                }
            }
        }
    }
}

// ---------------------------------------------------------------------------
// 4) Flash attention per (bn, h), max-free softmax, BARRIER-FREE:
//    K and V^T MFMA B-fragments are loaded directly from global (coalesced
//    16B/lane, L2-hot per combo); the ones-column B-frag is a register
//    constant; only P round-trips through LDS and its rows are wave-private.
// qk: [8192][2048] bf16 (Q pre-scaled by 0.125*log2e); vt: [8192][1024] bf16
// (V^T per combo); ob: [8192][1024] bf16.
__global__ __launch_bounds__(256) void attn(const u16* __restrict__ qk,
                                            const u16* __restrict__ vt,
                                            u16* __restrict__ ob) {
    __shared__ u16 Ps[128 * 72];
    const int tid = threadIdx.x;
    const int w = tid >> 6, l = tid & 63, q = l >> 4, c = l & 15;
    const int qtile = blockIdx.x, combo = blockIdx.y;
    const int bn = combo >> 4, h = combo & 15;
    const int t0 = bn << 10;
    const int qoff = h << 6;
    const int koff = 1024 + (h << 6);
    const int vrow0 = combo << 6;
    const int qrow_base = t0 + qtile * 128 + w * 32;

    // ones-column B-fragment (column 0 of the virtual ones tile): reg constant
    short8 v1;
    {
        u16 one = (c == 0) ? (u16)0x3F80 : (u16)0;
#pragma unroll
        for (int j = 0; j < 8; j++) v1[j] = (short)one;
    }

    // Q fragments (A-layout): rows qrow_base+mt*16+c, k = ks*32+q*8+j
    short8 aq[2][2];
#pragma unroll
    for (int mt = 0; mt < 2; mt++)
#pragma unroll
        for (int ks = 0; ks < 2; ks++)
            aq[mt][ks] = *reinterpret_cast<const short8*>(
                qk + (size_t)(qrow_base + mt * 16 + c) * 2048 + qoff + ks * 32 + q * 8);

    float4v o_acc[2][4];
    float4v osum[2];
#pragma unroll
    for (int mt = 0; mt < 2; mt++) {
#pragma unroll
        for (int nt = 0; nt < 4; nt++) o_acc[mt][nt] = {0.f, 0.f, 0.f, 0.f};
        osum[mt] = {0.f, 0.f, 0.f, 0.f};
    }

    // per-lane base pointers for direct B-frag loads
    const u16* kfrag = qk + (size_t)(t0 + c) * 2048 + koff + q * 8;   // +nt*16 rows, +ks*32, +key0 rows
    const u16* vfrag = vt + (size_t)(vrow0 + c) * 1024 + q * 8;       // +nt*16 rows, +ks*32, +key0 cols

    for (int chunk = 0; chunk < 16; chunk++) {
        const int key0 = chunk * 64;

        // K B-frags direct from global (L2-hot)
        short8 bk[2][4];
#pragma unroll
        for (int ks = 0; ks < 2; ks++)
#pragma unroll
            for (int nt = 0; nt < 4; nt++)
                bk[ks][nt] = *reinterpret_cast<const short8*>(
                    kfrag + (size_t)(key0 + nt * 16) * 2048 + ks * 32);

        // S = Q K^T (Q carries 0.125*log2e)
        float4v s[2][4];
#pragma unroll
        for (int mt = 0; mt < 2; mt++)
#pragma unroll
            for (int nt = 0; nt < 4; nt++) s[mt][nt] = {0.f, 0.f, 0.f, 0.f};
#pragma unroll
        for (int ks = 0; ks < 2; ks++)
#pragma unroll
            for (int mt = 0; mt < 2; mt++)
#pragma unroll
                for (int nt = 0; nt < 4; nt++)
                    s[mt][nt] = __builtin_amdgcn_mfma_f32_16x16x32_bf16(aq[mt][ks], bk[ks][nt], s[mt][nt], 0, 0, 0);

        // V^T B-frags direct from global — issued before exp so the latency
        // overlaps the transcendental section
        short8 vf[2][4];
#pragma unroll
        for (int ks = 0; ks < 2; ks++)
#pragma unroll
            for (int nt = 0; nt < 4; nt++)
                vf[ks][nt] = *reinterpret_cast<const short8*>(
                    vfrag + (size_t)(nt * 16) * 1024 + key0 + ks * 32);

        // max-free softmax numerator -> Ps (wave-private rows, no barrier)
#pragma unroll
        for (int mt = 0; mt < 2; mt++)
#pragma unroll
            for (int r = 0; r < 4; r++)
#pragma unroll
                for (int nt = 0; nt < 4; nt++)
                    Ps[(w * 32 + mt * 16 + q * 4 + r) * 72 + nt * 16 + c] =
                        f2b(EXP2F(s[mt][nt][r]));

        // O += P V ; osum += P @ ones
#pragma unroll
        for (int ks = 0; ks < 2; ks++) {
            short8 pf[2];
#pragma unroll
            for (int mt = 0; mt < 2; mt++)
                pf[mt] = *reinterpret_cast<const short8*>(
                    &Ps[(w * 32 + mt * 16 + c) * 72 + ks * 32 + q * 8]);
#pragma unroll
            for (int mt = 0; mt < 2; mt++) {
#pragma unroll
                for (int nt = 0; nt < 4; nt++)
                    o_acc[mt][nt] = __builtin_amdgcn_mfma_f32_16x16x32_bf16(pf[mt], vf[ks][nt], o_acc[mt][nt], 0, 0, 0);
                osum[mt] = __builtin_amdgcn_mfma_f32_16x16x32_bf16(pf[mt], v1, osum[mt], 0, 0, 0);
            }
        }
    }

    // epilogue: l lives in col 0 of osum (lane c==0 of each q group)
#pragma unroll
    for (int mt = 0; mt < 2; mt++) {
        float inv[4];
#pragma unroll
        for (int r = 0; r < 4; r++) {
            float lv = __shfl(osum[mt][r], tid & 48);   // lane (q,0) of this wave
            inv[r] = 1.0f / lv;
        }
#pragma unroll
        for (int nt = 0; nt < 4; nt++)
#pragma unroll
            for (int r = 0; r < 4; r++) {
                int row = qrow_base + mt * 16 + q * 4 + r;
                int col = (h << 6) + nt * 16 + c;
                ob[(size_t)row * 1024 + col] = f2b(o_acc[mt][nt][r] * inv[r]);
            }
    }
}

// ---------------------------------------------------------------------------
extern "C" void kernel_launch(void* const* d_in, const int* in_sizes, int n_in,
                              void* d_out, int out_size, void* d_ws, size_t ws_size,
                              hipStream_t stream) {
    const float* x    = (const float*)d_in[0];
    const float* wqkv = (const float*)d_in[1];
    const float* bqkv = (const float*)d_in[2];
    const float* wo   = (const float*)d_in[3];
    const float* bo   = (const float*)d_in[4];
    float* out = (float*)d_out;
    char* ws = (char*)d_ws;

    u16* xb    = (u16*)(ws);                 // [8192][1024]  16.8 MB
    u16* wqkvT = (u16*)(ws + 16777216);      // [3072][1024]   6.3 MB
    u16* woT   = (u16*)(ws + 23068672);      // [1024][1024]   2.1 MB
    u16* qkb   = (u16*)(ws + 25165824);      // [8192][2048]  33.6 MB
    u16* vtb   = (u16*)(ws + 58720256);      // [8192][1024]  16.8 MB (V^T per combo)
    u16* obuf  = (u16*)(ws + 75497472);      // [8192][1024]  16.8 MB
    // total 92.3 MB

    convert_x<<<8192, 256, 0, stream>>>(x, xb);
    transpose_convert<<<dim3(96, 32), dim3(32, 8), 0, stream>>>(wqkv, wqkvT, 1024, 3072);
    transpose_convert<<<dim3(32, 32), dim3(32, 8), 0, stream>>>(wo, woT, 1024, 1024);
    gemm_bt<1><<<dim3(24, 64), 256, 0, stream>>>(xb, wqkvT, bqkv,
                                                 nullptr, qkb, vtb, 8192, 3072, 1024);
    attn<<<dim3(8, 128), 256, 0, stream>>>(qkb, vtb, obuf);
    gemm_bt<0><<<dim3(8, 64), 256, 0, stream>>>(obuf, woT, bo,
                                                out, nullptr, nullptr, 8192, 1024, 1024);
}

// Round 4
// 278.917 us; speedup vs baseline: 1.3121x; 1.3121x over previous
//
#include <hip/hip_runtime.h>
#include <hip/hip_bf16.h>
#include <stdint.h>

typedef __attribute__((ext_vector_type(8))) short short8;
typedef __attribute__((ext_vector_type(4))) float float4v;
typedef __attribute__((ext_vector_type(4))) unsigned int uint4v;
typedef unsigned short u16;

#if __has_builtin(__builtin_amdgcn_exp2f)
#define EXP2F(x) __builtin_amdgcn_exp2f(x)
#else
#define EXP2F(x) __expf(0.69314718056f * (x))
#endif

__device__ __forceinline__ u16 f2b(float f) {
    union { __hip_bfloat16 b; u16 u; } cv;
    cv.b = __float2bfloat16(f);
    return cv.u;
}

#define GLD16(g, l) __builtin_amdgcn_global_load_lds( \
    (const __attribute__((address_space(1))) void*)(g), \
    (__attribute__((address_space(3))) void*)(l), 16, 0, 0)

// ---------------------------------------------------------------------------
// 1) Gather even rows of x (token t <- x row 2t) and convert fp32 -> bf16.
__global__ void convert_x(const float* __restrict__ x, u16* __restrict__ xb) {
    int id = blockIdx.x * 256 + threadIdx.x;
    int row = id >> 8;
    int c4 = id & 255;
    const float4* src = reinterpret_cast<const float4*>(x + (size_t)(2 * row) * 1024) + c4;
    float4 v = *src;
    ushort4 o;
    o.x = f2b(v.x); o.y = f2b(v.y); o.z = f2b(v.z); o.w = f2b(v.w);
    *(reinterpret_cast<ushort4*>(xb + (size_t)row * 1024) + c4) = o;
}

// ---------------------------------------------------------------------------
// 2) Transpose-convert: in fp32 [K][N] -> out bf16 [N][K].
__global__ void transpose_convert(const float* __restrict__ in, u16* __restrict__ out,
                                  int K, int N) {
    __shared__ float tile[32][33];
    int n0 = blockIdx.x * 32, k0 = blockIdx.y * 32;
    int tx = threadIdx.x, ty = threadIdx.y;       // 32 x 8
#pragma unroll
    for (int i = 0; i < 4; i++)
        tile[ty + i * 8][tx] = in[(size_t)(k0 + ty + i * 8) * N + n0 + tx];
    __syncthreads();
#pragma unroll
    for (int i = 0; i < 4; i++)
        out[(size_t)(n0 + ty + i * 8) * K + k0 + tx] = f2b(tile[tx][ty + i * 8]);
}

// ---------------------------------------------------------------------------
// 3) GEMM C = A @ BT + bias.  A bf16 [M][K], BT bf16 [N][K].
// MODE 0: C fp32 [M][N].
// MODE 1: QKV split: Q cols (<1024) pre-scaled by 0.125*log2(e); Q/K -> Cqk bf16
//         [M][2048]; V -> transposed Cvt bf16 [(bn*1024+(n-2048))][1024] col=key.
template <int MODE>
__global__ __launch_bounds__(256) void gemm_bt(
    const u16* __restrict__ A, const u16* __restrict__ BT,
    const float* __restrict__ bias,
    float* __restrict__ Cf, u16* __restrict__ Cqk, u16* __restrict__ Cvt,
    int M, int N, int K) {
    __shared__ u16 As[128 * 32];
    __shared__ u16 Bs[128 * 32];
    const int tid = threadIdx.x;
    const int w = tid >> 6, l = tid & 63;
    const int q = l >> 4, c = l & 15;
    const int m0 = blockIdx.y * 128, n0 = blockIdx.x * 128;
    const int wm = (w >> 1) * 64, wn = (w & 1) * 64;

    const int srow = w * 16 + (l >> 2);
    const int scol = (l & 3) * 8;
    const u16* gA = A + (size_t)(m0 + srow) * K + scol;
    const u16* gB = BT + (size_t)(n0 + srow) * K + scol;

    float4v acc[4][4];
#pragma unroll
    for (int i = 0; i < 4; i++)
#pragma unroll
        for (int j = 0; j < 4; j++) acc[i][j] = {0.f, 0.f, 0.f, 0.f};

    char* AsB = (char*)&As[0];
    char* BsB = (char*)&Bs[0];

    for (int k0 = 0; k0 < K; k0 += 32) {
        __syncthreads();
        GLD16(gA + k0,                  AsB + w * 1024);
        GLD16(gA + (size_t)64 * K + k0, AsB + 4096 + w * 1024);
        GLD16(gB + k0,                  BsB + w * 1024);
        GLD16(gB + (size_t)64 * K + k0, BsB + 4096 + w * 1024);
        __syncthreads();
        short8 af[4], bf[4];
#pragma unroll
        for (int mt = 0; mt < 4; mt++)
            af[mt] = *reinterpret_cast<const short8*>(&As[(wm + mt * 16 + c) * 32 + q * 8]);
#pragma unroll
        for (int nt = 0; nt < 4; nt++)
            bf[nt] = *reinterpret_cast<const short8*>(&Bs[(wn + nt * 16 + c) * 32 + q * 8]);
#pragma unroll
        for (int mt = 0; mt < 4; mt++)
#pragma unroll
            for (int nt = 0; nt < 4; nt++)
                acc[mt][nt] = __builtin_amdgcn_mfma_f32_16x16x32_bf16(af[mt], bf[nt], acc[mt][nt], 0, 0, 0);
    }

    const int q4 = q * 4;
    if (MODE == 0) {
#pragma unroll
        for (int nt = 0; nt < 4; nt++) {
            int col = n0 + wn + nt * 16 + c;
            float bv = bias[col];
#pragma unroll
            for (int mt = 0; mt < 4; mt++) {
                int row = m0 + wm + mt * 16 + q4;
#pragma unroll
                for (int r = 0; r < 4; r++)
                    Cf[(size_t)(row + r) * N + col] = acc[mt][nt][r] + bv;
            }
        }
    } else {
        bool isV = (n0 + wn) >= 2048;                       // wave-uniform
        float qscale = ((n0 + wn) < 1024) ? (0.125f * 1.44269504f) : 1.0f;
#pragma unroll
        for (int nt = 0; nt < 4; nt++) {
            int col = n0 + wn + nt * 16 + c;
            float bv = bias[col];
            if (!isV) {
#pragma unroll
                for (int mt = 0; mt < 4; mt++) {
                    int row = m0 + wm + mt * 16 + q4;
#pragma unroll
                    for (int r = 0; r < 4; r++)
                        Cqk[(size_t)(row + r) * 2048 + col] = f2b((acc[mt][nt][r] + bv) * qscale);
                }
            } else {
                int hd_ = col - 2048;                       // h*64 + d
#pragma unroll
                for (int mt = 0; mt < 4; mt++) {
                    int row = m0 + wm + mt * 16 + q4;       // multiple of 4
                    int bn = row >> 10, key = row & 1023;   // key..key+3 contiguous
                    ushort4 pk;
                    pk.x = f2b(acc[mt][nt][0] + bv);
                    pk.y = f2b(acc[mt][nt][1] + bv);
                    pk.z = f2b(acc[mt][nt][2] + bv);
                    pk.w = f2b(acc[mt][nt][3] + bv);
                    *reinterpret_cast<ushort4*>(
                        &Cvt[((size_t)(bn << 10) + hd_) * 1024 + key]) = pk;
                }
            }
        }
    }
}

// ---------------------------------------------------------------------------
// 4) Flash attention per (bn, h), max-free softmax (exact: scores bounded),
//    LDS-staged K/V with REGISTER PREFETCH: global loads for chunk c+1 are
//    issued at the top of chunk c's compute, so their latency overlaps the
//    MFMA/exp work; the end-of-chunk barrier pair only covers the ds_writes.
//    Ones-column B-frag is a register constant (row-sums via MFMA).
// qk: [8192][2048] bf16 (Q pre-scaled by 0.125*log2e); vt: [8192][1024] bf16
// (V^T per combo); ob: [8192][1024] bf16.
__global__ __launch_bounds__(256) void attn(const u16* __restrict__ qk,
                                            const u16* __restrict__ vt,
                                            u16* __restrict__ ob) {
    __shared__ u16 Ks[64 * 72];
    __shared__ u16 Vs[64 * 72];
    __shared__ u16 Ps[128 * 72];
    const int tid = threadIdx.x;
    const int w = tid >> 6, l = tid & 63, q = l >> 4, c = l & 15;
    const int qtile = blockIdx.x, combo = blockIdx.y;
    const int bn = combo >> 4, h = combo & 15;
    const int t0 = bn << 10;
    const int qoff = h << 6;
    const int koff = 1024 + (h << 6);
    const int vrow0 = combo << 6;
    const int qrow_base = t0 + qtile * 128 + w * 32;

    // ones-column B-fragment: lane c==0 holds 1.0 in all k slots
    short8 v1;
    {
        u16 one = (c == 0) ? (u16)0x3F80 : (u16)0;
#pragma unroll
        for (int j = 0; j < 8; j++) v1[j] = (short)one;
    }

    // Q fragments (A-layout): rows qrow_base+mt*16+c, k = ks*32+q*8+j
    short8 aq[2][2];
#pragma unroll
    for (int mt = 0; mt < 2; mt++)
#pragma unroll
        for (int ks = 0; ks < 2; ks++)
            aq[mt][ks] = *reinterpret_cast<const short8*>(
                qk + (size_t)(qrow_base + mt * 16 + c) * 2048 + qoff + ks * 32 + q * 8);

    float4v o_acc[2][4];
    float4v osum[2];
#pragma unroll
    for (int mt = 0; mt < 2; mt++) {
#pragma unroll
        for (int nt = 0; nt < 4; nt++) o_acc[mt][nt] = {0.f, 0.f, 0.f, 0.f};
        osum[mt] = {0.f, 0.f, 0.f, 0.f};
    }

    // staging coords: 256 threads cover 64 rows x 64 cols in 2 issues
    const int sr = tid >> 3;        // 0..31 (+32 second issue)
    const int sc = (tid & 7) * 8;   // 8-ushort chunk

    uint4v kreg[2], vreg[2];
    // prologue: chunk 0 -> regs -> LDS
#pragma unroll
    for (int i = 0; i < 2; i++) {
        int r = sr + i * 32;
        kreg[i] = *reinterpret_cast<const uint4v*>(
            qk + (size_t)(t0 + r) * 2048 + koff + sc);
        vreg[i] = *reinterpret_cast<const uint4v*>(
            vt + (size_t)(vrow0 + r) * 1024 + sc);
    }
#pragma unroll
    for (int i = 0; i < 2; i++) {
        int r = sr + i * 32;
        *reinterpret_cast<uint4v*>(&Ks[r * 72 + sc]) = kreg[i];
        *reinterpret_cast<uint4v*>(&Vs[r * 72 + sc]) = vreg[i];
    }
    __syncthreads();

    for (int chunk = 0; chunk < 16; chunk++) {
        // prefetch next chunk into registers (latency overlaps compute below)
        if (chunk < 15) {
            const int key0n = (chunk + 1) * 64;
#pragma unroll
            for (int i = 0; i < 2; i++) {
                int r = sr + i * 32;
                kreg[i] = *reinterpret_cast<const uint4v*>(
                    qk + (size_t)(t0 + key0n + r) * 2048 + koff + sc);
                vreg[i] = *reinterpret_cast<const uint4v*>(
                    vt + (size_t)(vrow0 + r) * 1024 + key0n + sc);
            }
        }

        // S = Q K^T (Q carries 0.125*log2e)
        float4v s[2][4];
#pragma unroll
        for (int mt = 0; mt < 2; mt++)
#pragma unroll
            for (int nt = 0; nt < 4; nt++) s[mt][nt] = {0.f, 0.f, 0.f, 0.f};
#pragma unroll
        for (int ks = 0; ks < 2; ks++) {
            short8 bk[4];
#pragma unroll
            for (int nt = 0; nt < 4; nt++)
                bk[nt] = *reinterpret_cast<const short8*>(&Ks[(nt * 16 + c) * 72 + ks * 32 + q * 8]);
#pragma unroll
            for (int mt = 0; mt < 2; mt++)
#pragma unroll
                for (int nt = 0; nt < 4; nt++)
                    s[mt][nt] = __builtin_amdgcn_mfma_f32_16x16x32_bf16(aq[mt][ks], bk[nt], s[mt][nt], 0, 0, 0);
        }

        // max-free softmax numerator -> Ps (wave-private rows, no barrier)
#pragma unroll
        for (int mt = 0; mt < 2; mt++)
#pragma unroll
            for (int r = 0; r < 4; r++)
#pragma unroll
                for (int nt = 0; nt < 4; nt++)
                    Ps[(w * 32 + mt * 16 + q * 4 + r) * 72 + nt * 16 + c] =
                        f2b(EXP2F(s[mt][nt][r]));

        // O += P V ; osum += P @ ones
#pragma unroll
        for (int ks = 0; ks < 2; ks++) {
            short8 pf[2], vf[4];
#pragma unroll
            for (int mt = 0; mt < 2; mt++)
                pf[mt] = *reinterpret_cast<const short8*>(
                    &Ps[(w * 32 + mt * 16 + c) * 72 + ks * 32 + q * 8]);
#pragma unroll
            for (int nt = 0; nt < 4; nt++)
                vf[nt] = *reinterpret_cast<const short8*>(&Vs[(nt * 16 + c) * 72 + ks * 32 + q * 8]);
#pragma unroll
            for (int mt = 0; mt < 2; mt++) {
#pragma unroll
                for (int nt = 0; nt < 4; nt++)
                    o_acc[mt][nt] = __builtin_amdgcn_mfma_f32_16x16x32_bf16(pf[mt], vf[nt], o_acc[mt][nt], 0, 0, 0);
                osum[mt] = __builtin_amdgcn_mfma_f32_16x16x32_bf16(pf[mt], v1, osum[mt], 0, 0, 0);
            }
        }

        // swap in prefetched chunk: only LDS-write latency between barriers
        if (chunk < 15) {
            __syncthreads();
#pragma unroll
            for (int i = 0; i < 2; i++) {
                int r = sr + i * 32;
                *reinterpret_cast<uint4v*>(&Ks[r * 72 + sc]) = kreg[i];
                *reinterpret_cast<uint4v*>(&Vs[r * 72 + sc]) = vreg[i];
            }
            __syncthreads();
        }
    }

    // epilogue: l lives in col 0 of osum (lane c==0 of each q group)
#pragma unroll
    for (int mt = 0; mt < 2; mt++) {
        float inv[4];
#pragma unroll
        for (int r = 0; r < 4; r++) {
            float lv = __shfl(osum[mt][r], tid & 48);   // lane (q,0) of this wave
            inv[r] = 1.0f / lv;
        }
#pragma unroll
        for (int nt = 0; nt < 4; nt++)
#pragma unroll
            for (int r = 0; r < 4; r++) {
                int row = qrow_base + mt * 16 + q * 4 + r;
                int col = (h << 6) + nt * 16 + c;
                ob[(size_t)row * 1024 + col] = f2b(o_acc[mt][nt][r] * inv[r]);
            }
    }
}

// ---------------------------------------------------------------------------
extern "C" void kernel_launch(void* const* d_in, const int* in_sizes, int n_in,
                              void* d_out, int out_size, void* d_ws, size_t ws_size,
                              hipStream_t stream) {
    const float* x    = (const float*)d_in[0];
    const float* wqkv = (const float*)d_in[1];
    const float* bqkv = (const float*)d_in[2];
    const float* wo   = (const float*)d_in[3];
    const float* bo   = (const float*)d_in[4];
    float* out = (float*)d_out;
    char* ws = (char*)d_ws;

    u16* xb    = (u16*)(ws);                 // [8192][1024]  16.8 MB
    u16* wqkvT = (u16*)(ws + 16777216);      // [3072][1024]   6.3 MB
    u16* woT   = (u16*)(ws + 23068672);      // [1024][1024]   2.1 MB
    u16* qkb   = (u16*)(ws + 25165824);      // [8192][2048]  33.6 MB
    u16* vtb   = (u16*)(ws + 58720256);      // [8192][1024]  16.8 MB (V^T per combo)
    u16* obuf  = (u16*)(ws + 75497472);      // [8192][1024]  16.8 MB
    // total 92.3 MB

    convert_x<<<8192, 256, 0, stream>>>(x, xb);
    transpose_convert<<<dim3(96, 32), dim3(32, 8), 0, stream>>>(wqkv, wqkvT, 1024, 3072);
    transpose_convert<<<dim3(32, 32), dim3(32, 8), 0, stream>>>(wo, woT, 1024, 1024);
    gemm_bt<1><<<dim3(24, 64), 256, 0, stream>>>(xb, wqkvT, bqkv,
                                                 nullptr, qkb, vtb, 8192, 3072, 1024);
    attn<<<dim3(8, 128), 256, 0, stream>>>(qkb, vtb, obuf);
    gemm_bt<0><<<dim3(8, 64), 256, 0, stream>>>(obuf, woT, bo,
                                                out, nullptr, nullptr, 8192, 1024, 1024);
}

// Round 5
// 259.131 us; speedup vs baseline: 1.4123x; 1.0764x over previous
//
#include <hip/hip_runtime.h>
#include <hip/hip_bf16.h>
#include <stdint.h>

typedef __attribute__((ext_vector_type(8))) short short8;
typedef __attribute__((ext_vector_type(4))) float float4v;
typedef __attribute__((ext_vector_type(4))) unsigned int uint4v;
typedef unsigned short u16;

#if __has_builtin(__builtin_amdgcn_exp2f)
#define EXP2F(x) __builtin_amdgcn_exp2f(x)
#else
#define EXP2F(x) __expf(0.69314718056f * (x))
#endif

__device__ __forceinline__ u16 f2b(float f) {
    union { __hip_bfloat16 b; u16 u; } cv;
    cv.b = __float2bfloat16(f);
    return cv.u;
}

#define GLD16(g, l) __builtin_amdgcn_global_load_lds( \
    (const __attribute__((address_space(1))) void*)(g), \
    (__attribute__((address_space(3))) void*)(l), 16, 0, 0)

// ---------------------------------------------------------------------------
// 1) Gather even rows of x (token t <- x row 2t) and convert fp32 -> bf16.
__global__ void convert_x(const float* __restrict__ x, u16* __restrict__ xb) {
    int id = blockIdx.x * 256 + threadIdx.x;
    int row = id >> 8;
    int c4 = id & 255;
    const float4* src = reinterpret_cast<const float4*>(x + (size_t)(2 * row) * 1024) + c4;
    float4 v = *src;
    ushort4 o;
    o.x = f2b(v.x); o.y = f2b(v.y); o.z = f2b(v.z); o.w = f2b(v.w);
    *(reinterpret_cast<ushort4*>(xb + (size_t)row * 1024) + c4) = o;
}

// ---------------------------------------------------------------------------
// 2) Transpose-convert: in fp32 [K][N] -> out bf16 [N][K].
__global__ void transpose_convert(const float* __restrict__ in, u16* __restrict__ out,
                                  int K, int N) {
    __shared__ float tile[32][33];
    int n0 = blockIdx.x * 32, k0 = blockIdx.y * 32;
    int tx = threadIdx.x, ty = threadIdx.y;       // 32 x 8
#pragma unroll
    for (int i = 0; i < 4; i++)
        tile[ty + i * 8][tx] = in[(size_t)(k0 + ty + i * 8) * N + n0 + tx];
    __syncthreads();
#pragma unroll
    for (int i = 0; i < 4; i++)
        out[(size_t)(n0 + ty + i * 8) * K + k0 + tx] = f2b(tile[tx][ty + i * 8]);
}

// ---------------------------------------------------------------------------
// 3) GEMM C = A @ BT + bias.  A bf16 [M][K], BT bf16 [N][K].
// BK=64 with XOR chunk swizzle: LDS row pitch = 64 u16 (128 B); 16B chunk p of
// row r is stored at physical slot p^(r&7) (chosen at staging time via the
// global address — global_load_lds dest is lane-ordered and can't pad).
// Readers de-swizzle; frag reads then hit 8 distinct 4-bank sets (2-way, free).
// MODE 0: C fp32 [M][N].
// MODE 1: QKV split: Q cols (<1024) pre-scaled by 0.125*log2(e); Q/K -> Cqk bf16
//         [M][2048]; V -> transposed Cvt bf16 [(bn*1024+(n-2048))][1024] col=key.
template <int MODE>
__global__ __launch_bounds__(256) void gemm_bt(
    const u16* __restrict__ A, const u16* __restrict__ BT,
    const float* __restrict__ bias,
    float* __restrict__ Cf, u16* __restrict__ Cqk, u16* __restrict__ Cvt,
    int M, int N, int K) {
    __shared__ u16 As[128 * 64];
    __shared__ u16 Bs[128 * 64];
    const int tid = threadIdx.x;
    const int w = tid >> 6, l = tid & 63;
    const int q = l >> 4, c = l & 15;
    const int m0 = blockIdx.y * 128, n0 = blockIdx.x * 128;
    const int wm = (w >> 1) * 64, wn = (w & 1) * 64;

    // staging: per issue j (0..3): rows j*32 + w*8 + (l>>3); chunk = l&7 (16B)
    // global column chunk = (l&7) ^ (row&7)  [row&7 == srow&7, j*32 preserves]
    const int srow = w * 8 + (l >> 3);
    const int scol = ((l & 7) ^ (srow & 7)) * 8;   // u16 units
    const u16* gA = A + (size_t)(m0 + srow) * K + scol;
    const u16* gB = BT + (size_t)(n0 + srow) * K + scol;
    char* AsB = (char*)&As[0];
    char* BsB = (char*)&Bs[0];
    const int ldsOff = (w * 8) * 128;              // + j*32*128 per issue

    float4v acc[4][4];
#pragma unroll
    for (int i = 0; i < 4; i++)
#pragma unroll
        for (int j = 0; j < 4; j++) acc[i][j] = {0.f, 0.f, 0.f, 0.f};

    // de-swizzled physical chunk offsets for frag reads (row&7 == c&7)
    const int cs = c & 7;

    for (int k0 = 0; k0 < K; k0 += 64) {
        __syncthreads();
#pragma unroll
        for (int j = 0; j < 4; j++) {
            GLD16(gA + (size_t)(j * 32) * K + k0, AsB + ldsOff + j * 32 * 128);
            GLD16(gB + (size_t)(j * 32) * K + k0, BsB + ldsOff + j * 32 * 128);
        }
        __syncthreads();
#pragma unroll
        for (int kk = 0; kk < 2; kk++) {
            const int phys = ((kk * 4 + q) ^ cs) * 8;   // u16 offset within row
            short8 af[4], bf[4];
#pragma unroll
            for (int mt = 0; mt < 4; mt++)
                af[mt] = *reinterpret_cast<const short8*>(&As[(wm + mt * 16 + c) * 64 + phys]);
#pragma unroll
            for (int nt = 0; nt < 4; nt++)
                bf[nt] = *reinterpret_cast<const short8*>(&Bs[(wn + nt * 16 + c) * 64 + phys]);
#pragma unroll
            for (int mt = 0; mt < 4; mt++)
#pragma unroll
                for (int nt = 0; nt < 4; nt++)
                    acc[mt][nt] = __builtin_amdgcn_mfma_f32_16x16x32_bf16(af[mt], bf[nt], acc[mt][nt], 0, 0, 0);
        }
    }

    const int q4 = q * 4;
    if (MODE == 0) {
#pragma unroll
        for (int nt = 0; nt < 4; nt++) {
            int col = n0 + wn + nt * 16 + c;
            float bv = bias[col];
#pragma unroll
            for (int mt = 0; mt < 4; mt++) {
                int row = m0 + wm + mt * 16 + q4;
#pragma unroll
                for (int r = 0; r < 4; r++)
                    Cf[(size_t)(row + r) * N + col] = acc[mt][nt][r] + bv;
            }
        }
    } else {
        bool isV = (n0 + wn) >= 2048;                       // wave-uniform
        float qscale = ((n0 + wn) < 1024) ? (0.125f * 1.44269504f) : 1.0f;
#pragma unroll
        for (int nt = 0; nt < 4; nt++) {
            int col = n0 + wn + nt * 16 + c;
            float bv = bias[col];
            if (!isV) {
#pragma unroll
                for (int mt = 0; mt < 4; mt++) {
                    int row = m0 + wm + mt * 16 + q4;
#pragma unroll
                    for (int r = 0; r < 4; r++)
                        Cqk[(size_t)(row + r) * 2048 + col] = f2b((acc[mt][nt][r] + bv) * qscale);
                }
            } else {
                int hd_ = col - 2048;                       // h*64 + d
#pragma unroll
                for (int mt = 0; mt < 4; mt++) {
                    int row = m0 + wm + mt * 16 + q4;       // multiple of 4
                    int bn = row >> 10, key = row & 1023;   // key..key+3 contiguous
                    ushort4 pk;
                    pk.x = f2b(acc[mt][nt][0] + bv);
                    pk.y = f2b(acc[mt][nt][1] + bv);
                    pk.z = f2b(acc[mt][nt][2] + bv);
                    pk.w = f2b(acc[mt][nt][3] + bv);
                    *reinterpret_cast<ushort4*>(
                        &Cvt[((size_t)(bn << 10) + hd_) * 1024 + key]) = pk;
                }
            }
        }
    }
}

// ---------------------------------------------------------------------------
// 4) Flash attention per (bn, h), max-free softmax, LDS K/V with register
//    prefetch; ones-column row-sums via MFMA. Grid: x=combo (128), y=qtile (8)
//    so all q-tiles of a combo land on one XCD (idx%8 == combo%8) -> L2 reuse.
__global__ __launch_bounds__(256) void attn(const u16* __restrict__ qk,
                                            const u16* __restrict__ vt,
                                            u16* __restrict__ ob) {
    __shared__ u16 Ks[64 * 72];
    __shared__ u16 Vs[64 * 72];
    __shared__ u16 Ps[128 * 72];
    const int tid = threadIdx.x;
    const int w = tid >> 6, l = tid & 63, q = l >> 4, c = l & 15;
    const int combo = blockIdx.x, qtile = blockIdx.y;
    const int bn = combo >> 4, h = combo & 15;
    const int t0 = bn << 10;
    const int qoff = h << 6;
    const int koff = 1024 + (h << 6);
    const int vrow0 = combo << 6;
    const int qrow_base = t0 + qtile * 128 + w * 32;

    // ones-column B-fragment: lane c==0 holds 1.0 in all k slots
    short8 v1;
    {
        u16 one = (c == 0) ? (u16)0x3F80 : (u16)0;
#pragma unroll
        for (int j = 0; j < 8; j++) v1[j] = (short)one;
    }

    // Q fragments (A-layout): rows qrow_base+mt*16+c, k = ks*32+q*8+j
    short8 aq[2][2];
#pragma unroll
    for (int mt = 0; mt < 2; mt++)
#pragma unroll
        for (int ks = 0; ks < 2; ks++)
            aq[mt][ks] = *reinterpret_cast<const short8*>(
                qk + (size_t)(qrow_base + mt * 16 + c) * 2048 + qoff + ks * 32 + q * 8);

    float4v o_acc[2][4];
    float4v osum[2];
#pragma unroll
    for (int mt = 0; mt < 2; mt++) {
#pragma unroll
        for (int nt = 0; nt < 4; nt++) o_acc[mt][nt] = {0.f, 0.f, 0.f, 0.f};
        osum[mt] = {0.f, 0.f, 0.f, 0.f};
    }

    const int sr = tid >> 3;        // 0..31 (+32 second issue)
    const int sc = (tid & 7) * 8;   // 8-ushort chunk

    uint4v kreg[2], vreg[2];
#pragma unroll
    for (int i = 0; i < 2; i++) {
        int r = sr + i * 32;
        kreg[i] = *reinterpret_cast<const uint4v*>(
            qk + (size_t)(t0 + r) * 2048 + koff + sc);
        vreg[i] = *reinterpret_cast<const uint4v*>(
            vt + (size_t)(vrow0 + r) * 1024 + sc);
    }
#pragma unroll
    for (int i = 0; i < 2; i++) {
        int r = sr + i * 32;
        *reinterpret_cast<uint4v*>(&Ks[r * 72 + sc]) = kreg[i];
        *reinterpret_cast<uint4v*>(&Vs[r * 72 + sc]) = vreg[i];
    }
    __syncthreads();

    for (int chunk = 0; chunk < 16; chunk++) {
        if (chunk < 15) {
            const int key0n = (chunk + 1) * 64;
#pragma unroll
            for (int i = 0; i < 2; i++) {
                int r = sr + i * 32;
                kreg[i] = *reinterpret_cast<const uint4v*>(
                    qk + (size_t)(t0 + key0n + r) * 2048 + koff + sc);
                vreg[i] = *reinterpret_cast<const uint4v*>(
                    vt + (size_t)(vrow0 + r) * 1024 + key0n + sc);
            }
        }

        // S = Q K^T (Q carries 0.125*log2e)
        float4v s[2][4];
#pragma unroll
        for (int mt = 0; mt < 2; mt++)
#pragma unroll
            for (int nt = 0; nt < 4; nt++) s[mt][nt] = {0.f, 0.f, 0.f, 0.f};
#pragma unroll
        for (int ks = 0; ks < 2; ks++) {
            short8 bk[4];
#pragma unroll
            for (int nt = 0; nt < 4; nt++)
                bk[nt] = *reinterpret_cast<const short8*>(&Ks[(nt * 16 + c) * 72 + ks * 32 + q * 8]);
#pragma unroll
            for (int mt = 0; mt < 2; mt++)
#pragma unroll
                for (int nt = 0; nt < 4; nt++)
                    s[mt][nt] = __builtin_amdgcn_mfma_f32_16x16x32_bf16(aq[mt][ks], bk[nt], s[mt][nt], 0, 0, 0);
        }

        // max-free softmax numerator -> Ps (wave-private rows, no barrier)
#pragma unroll
        for (int mt = 0; mt < 2; mt++)
#pragma unroll
            for (int r = 0; r < 4; r++)
#pragma unroll
                for (int nt = 0; nt < 4; nt++)
                    Ps[(w * 32 + mt * 16 + q * 4 + r) * 72 + nt * 16 + c] =
                        f2b(EXP2F(s[mt][nt][r]));

        // O += P V ; osum += P @ ones
#pragma unroll
        for (int ks = 0; ks < 2; ks++) {
            short8 pf[2], vf[4];
#pragma unroll
            for (int mt = 0; mt < 2; mt++)
                pf[mt] = *reinterpret_cast<const short8*>(
                    &Ps[(w * 32 + mt * 16 + c) * 72 + ks * 32 + q * 8]);
#pragma unroll
            for (int nt = 0; nt < 4; nt++)
                vf[nt] = *reinterpret_cast<const short8*>(&Vs[(nt * 16 + c) * 72 + ks * 32 + q * 8]);
#pragma unroll
            for (int mt = 0; mt < 2; mt++) {
#pragma unroll
                for (int nt = 0; nt < 4; nt++)
                    o_acc[mt][nt] = __builtin_amdgcn_mfma_f32_16x16x32_bf16(pf[mt], vf[nt], o_acc[mt][nt], 0, 0, 0);
                osum[mt] = __builtin_amdgcn_mfma_f32_16x16x32_bf16(pf[mt], v1, osum[mt], 0, 0, 0);
            }
        }

        if (chunk < 15) {
            __syncthreads();
#pragma unroll
            for (int i = 0; i < 2; i++) {
                int r = sr + i * 32;
                *reinterpret_cast<uint4v*>(&Ks[r * 72 + sc]) = kreg[i];
                *reinterpret_cast<uint4v*>(&Vs[r * 72 + sc]) = vreg[i];
            }
            __syncthreads();
        }
    }

    // epilogue: l lives in col 0 of osum (lane c==0 of each q group)
#pragma unroll
    for (int mt = 0; mt < 2; mt++) {
        float inv[4];
#pragma unroll
        for (int r = 0; r < 4; r++) {
            float lv = __shfl(osum[mt][r], tid & 48);   // lane (q,0) of this wave
            inv[r] = 1.0f / lv;
        }
#pragma unroll
        for (int nt = 0; nt < 4; nt++)
#pragma unroll
            for (int r = 0; r < 4; r++) {
                int row = qrow_base + mt * 16 + q * 4 + r;
                int col = (h << 6) + nt * 16 + c;
                ob[(size_t)row * 1024 + col] = f2b(o_acc[mt][nt][r] * inv[r]);
            }
    }
}

// ---------------------------------------------------------------------------
extern "C" void kernel_launch(void* const* d_in, const int* in_sizes, int n_in,
                              void* d_out, int out_size, void* d_ws, size_t ws_size,
                              hipStream_t stream) {
    const float* x    = (const float*)d_in[0];
    const float* wqkv = (const float*)d_in[1];
    const float* bqkv = (const float*)d_in[2];
    const float* wo   = (const float*)d_in[3];
    const float* bo   = (const float*)d_in[4];
    float* out = (float*)d_out;
    char* ws = (char*)d_ws;

    u16* xb    = (u16*)(ws);                 // [8192][1024]  16.8 MB
    u16* wqkvT = (u16*)(ws + 16777216);      // [3072][1024]   6.3 MB
    u16* woT   = (u16*)(ws + 23068672);      // [1024][1024]   2.1 MB
    u16* qkb   = (u16*)(ws + 25165824);      // [8192][2048]  33.6 MB
    u16* vtb   = (u16*)(ws + 58720256);      // [8192][1024]  16.8 MB (V^T per combo)
    u16* obuf  = (u16*)(ws + 75497472);      // [8192][1024]  16.8 MB
    // total 92.3 MB

    convert_x<<<8192, 256, 0, stream>>>(x, xb);
    transpose_convert<<<dim3(96, 32), dim3(32, 8), 0, stream>>>(wqkv, wqkvT, 1024, 3072);
    transpose_convert<<<dim3(32, 32), dim3(32, 8), 0, stream>>>(wo, woT, 1024, 1024);
    gemm_bt<1><<<dim3(24, 64), 256, 0, stream>>>(xb, wqkvT, bqkv,
                                                 nullptr, qkb, vtb, 8192, 3072, 1024);
    attn<<<dim3(128, 8), 256, 0, stream>>>(qkb, vtb, obuf);
    gemm_bt<0><<<dim3(8, 64), 256, 0, stream>>>(obuf, woT, bo,
                                                out, nullptr, nullptr, 8192, 1024, 1024);
}